// Round 1
// baseline (926.396 us; speedup 1.0000x reference)
//
#include <hip/hip_runtime.h>
#include <cstdint>
#include <cstddef>

#define NN 100000
#define EE 1600000
#define ET 1700000          // EE + NN self-loops
#define NB 196              // ceil(NN/512)
#define STAT_BLOCKS 400
#define KC 32

__device__ __forceinline__ float leaky(float v) { return v > 0.f ? v : 0.2f * v; }
// pad: insert 4 floats (16B) every 64 floats -> b128 reads of 8-aligned groups are <=2-way bank aliased (free)
__device__ __forceinline__ int padidx(int i) { return i + ((i >> 6) << 2); }

// ---------------- CSR build ----------------
__global__ void k_count(const int* __restrict__ ei, int* __restrict__ cnt) {
    int e = blockIdx.x * 256 + threadIdx.x;
    if (e < ET) {
        int d = (e < EE) ? ei[EE + e] : (e - EE);
        atomicAdd(&cnt[d], 1);
    }
}

__global__ void k_partial(const int* __restrict__ cnt, int* __restrict__ bsum) {
    __shared__ int s[256];
    int t = threadIdx.x;
    int base = blockIdx.x * 512;
    int a = (base + t < NN) ? cnt[base + t] : 0;
    int b = (base + 256 + t < NN) ? cnt[base + 256 + t] : 0;
    s[t] = a + b;
    __syncthreads();
    for (int o = 128; o; o >>= 1) { if (t < o) s[t] += s[t + o]; __syncthreads(); }
    if (t == 0) bsum[blockIdx.x] = s[0];
}

__global__ void k_scanbsum(const int* __restrict__ bsum, int* __restrict__ bpre, int* __restrict__ off) {
    __shared__ int s[256];
    int t = threadIdx.x;
    int v = (t < NB) ? bsum[t] : 0;
    s[t] = v;
    __syncthreads();
    for (int o = 1; o < 256; o <<= 1) {
        int add = (t >= o) ? s[t - o] : 0;
        __syncthreads();
        s[t] += add;
        __syncthreads();
    }
    if (t < NB) bpre[t] = s[t] - v;      // exclusive prefix of block sums
    if (t == 255) off[NN] = s[255];      // total == ET
}

__global__ void k_scanoff(const int* __restrict__ cnt, const int* __restrict__ bpre, int* __restrict__ off) {
    __shared__ int s[512];
    int t = threadIdx.x;
    int g = blockIdx.x * 512 + t;
    int v = (g < NN) ? cnt[g] : 0;
    s[t] = v;
    __syncthreads();
    for (int o = 1; o < 512; o <<= 1) {
        int add = (t >= o) ? s[t - o] : 0;
        __syncthreads();
        s[t] += add;
        __syncthreads();
    }
    if (g < NN) off[g] = bpre[blockIdx.x] + s[t] - v;  // exclusive scan
}

__global__ void k_scatter(const int* __restrict__ ei, const int* __restrict__ off,
                          int* __restrict__ cur, int* __restrict__ srcs) {
    int e = blockIdx.x * 256 + threadIdx.x;
    if (e < ET) {
        int s, d;
        if (e < EE) { s = ei[e]; d = ei[EE + e]; } else { s = e - EE; d = s; }
        int pos = off[d] + atomicAdd(&cur[d], 1);
        srcs[pos] = s;
    }
}

// ---------------- GEMM: H = X @ W^T, fused input affine+relu, fused as/ad epilogue ----------------
template<bool AFFINE>
__global__ __launch_bounds__(256, 3) void k_gemm(
    const float* __restrict__ X, const float* __restrict__ Wm,
    const float* __restrict__ scale, const float* __restrict__ shift,
    const float* __restrict__ asrc, const float* __restrict__ adst,
    float* __restrict__ H, float* __restrict__ AS, float* __restrict__ AD)
{
    __shared__ float xsT[KC][136];
    __shared__ float wsT[KC][136];
    const int t = threadIdx.x;
    const int row0 = blockIdx.x * 128;
    const int r0 = (t >> 4) << 3;   // 0..120
    const int c0 = (t & 15) << 3;   // 0..120
    const int lr = t >> 3;          // 0..31
    const int lc = (t & 7) << 2;    // 0..28

    float acc[8][8];
#pragma unroll
    for (int i = 0; i < 8; ++i)
#pragma unroll
        for (int j = 0; j < 8; ++j) acc[i][j] = 0.f;

    for (int k0 = 0; k0 < 128; k0 += KC) {
        __syncthreads();
        float4 sc4, sh4;
        if (AFFINE) {
            sc4 = *(const float4*)&scale[k0 + lc];
            sh4 = *(const float4*)&shift[k0 + lc];
        }
#pragma unroll
        for (int p = 0; p < 4; ++p) {
            int r = p * 32 + lr;
            int grow = row0 + r;
            float4 v = make_float4(0.f, 0.f, 0.f, 0.f);
            if (grow < NN) v = *(const float4*)&X[(size_t)grow * 128 + k0 + lc];
            if (AFFINE) {
                v.x = fmaxf(0.f, fmaf(v.x, sc4.x, sh4.x));
                v.y = fmaxf(0.f, fmaf(v.y, sc4.y, sh4.y));
                v.z = fmaxf(0.f, fmaf(v.z, sc4.z, sh4.z));
                v.w = fmaxf(0.f, fmaf(v.w, sc4.w, sh4.w));
            }
            int pr = padidx(r);
            xsT[lc + 0][pr] = v.x; xsT[lc + 1][pr] = v.y;
            xsT[lc + 2][pr] = v.z; xsT[lc + 3][pr] = v.w;
        }
#pragma unroll
        for (int p = 0; p < 4; ++p) {
            int c = p * 32 + lr;
            float4 v = *(const float4*)&Wm[(size_t)c * 128 + k0 + lc];
            int pc = padidx(c);
            wsT[lc + 0][pc] = v.x; wsT[lc + 1][pc] = v.y;
            wsT[lc + 2][pc] = v.z; wsT[lc + 3][pc] = v.w;
        }
        __syncthreads();
        const int pr0 = padidx(r0), pc0 = padidx(c0);
#pragma unroll
        for (int kk = 0; kk < KC; ++kk) {
            float4 xa = *(const float4*)&xsT[kk][pr0];
            float4 xb = *(const float4*)&xsT[kk][pr0 + 4];
            float4 wa = *(const float4*)&wsT[kk][pc0];
            float4 wb = *(const float4*)&wsT[kk][pc0 + 4];
            float xr[8] = {xa.x, xa.y, xa.z, xa.w, xb.x, xb.y, xb.z, xb.w};
            float wr[8] = {wa.x, wa.y, wa.z, wa.w, wb.x, wb.y, wb.z, wb.w};
#pragma unroll
            for (int i = 0; i < 8; ++i)
#pragma unroll
                for (int j = 0; j < 8; ++j) acc[i][j] = fmaf(xr[i], wr[j], acc[i][j]);
        }
    }

    // epilogue: store H and fused as/ad (16-lane butterfly over the c-groups)
    float4 sa1 = *(const float4*)&asrc[c0];
    float4 sa2 = *(const float4*)&asrc[c0 + 4];
    float4 da1 = *(const float4*)&adst[c0];
    float4 da2 = *(const float4*)&adst[c0 + 4];
    float av[8] = {sa1.x, sa1.y, sa1.z, sa1.w, sa2.x, sa2.y, sa2.z, sa2.w};
    float dv[8] = {da1.x, da1.y, da1.z, da1.w, da2.x, da2.y, da2.z, da2.w};
#pragma unroll
    for (int i = 0; i < 8; ++i) {
        int grow = row0 + r0 + i;
        float ps = 0.f, pd = 0.f;
#pragma unroll
        for (int j = 0; j < 8; ++j) {
            ps = fmaf(acc[i][j], av[j], ps);
            pd = fmaf(acc[i][j], dv[j], pd);
        }
#pragma unroll
        for (int m = 1; m < 16; m <<= 1) { ps += __shfl_xor(ps, m); pd += __shfl_xor(pd, m); }
        if (grow < NN) {
            float4 o1 = make_float4(acc[i][0], acc[i][1], acc[i][2], acc[i][3]);
            float4 o2 = make_float4(acc[i][4], acc[i][5], acc[i][6], acc[i][7]);
            *(float4*)&H[(size_t)grow * 128 + c0] = o1;
            *(float4*)&H[(size_t)grow * 128 + c0 + 4] = o2;
            if ((t & 15) == 0) { AS[grow] = ps; AD[grow] = pd; }
        }
    }
}

// ---------------- per-dst-node softmax + aggregation (one wave per node) ----------------
__global__ __launch_bounds__(256) void k_agg(
    const int* __restrict__ off, const int* __restrict__ srcs,
    const float* __restrict__ H, const float* __restrict__ AS,
    const float* __restrict__ AD, const float* __restrict__ bias,
    float* __restrict__ OUT)
{
    __shared__ int   s_src[4][64];
    __shared__ float s_ev[4][64];
    const int wid  = threadIdx.x >> 6;
    const int lane = threadIdx.x & 63;
    const int n    = blockIdx.x * 4 + wid;
    const int beg = off[n], end = off[n + 1];
    const float adn = AD[n];

    // pass 1: segment max
    float m = -1e30f;
    for (int i = beg + lane; i < end; i += 64) {
        float e = leaky(AS[srcs[i]] + adn);
        m = fmaxf(m, e);
    }
#pragma unroll
    for (int o = 32; o; o >>= 1) m = fmaxf(m, __shfl_xor(m, o));

    // pass 2: unnormalized accumulate + denom
    float acc0 = 0.f, acc1 = 0.f, den = 0.f;
    for (int base = beg; base < end; base += 64) {
        int cnt = end - base; if (cnt > 64) cnt = 64;
        float ev = 0.f; int s = 0;
        if (lane < cnt) {
            s  = srcs[base + lane];
            ev = __expf(leaky(AS[s] + adn) - m);
        }
        s_src[wid][lane] = s;
        s_ev[wid][lane]  = ev;
        den += ev;
        for (int j = 0; j < cnt; ++j) {
            int   sj = s_src[wid][j];
            float w  = s_ev[wid][j];
            const float* hp = H + (size_t)sj * 128;
            acc0 = fmaf(w, hp[lane], acc0);
            acc1 = fmaf(w, hp[64 + lane], acc1);
        }
    }
#pragma unroll
    for (int o = 32; o; o >>= 1) den += __shfl_xor(den, o);
    float inv = 1.f / den;
    OUT[(size_t)n * 128 + lane]      = fmaf(acc0, inv, bias[lane]);
    OUT[(size_t)n * 128 + 64 + lane] = fmaf(acc1, inv, bias[64 + lane]);
}

// ---------------- batchnorm stats -> per-column affine ----------------
__global__ void k_colsum(const float* __restrict__ Xb, float* __restrict__ gsum, float* __restrict__ gsq) {
    __shared__ float ls[256], lq[256];
    int t = threadIdx.x;
    int c = t & 127, half = t >> 7;
    float s = 0.f, q = 0.f;
    for (int r = blockIdx.x * 2 + half; r < NN; r += STAT_BLOCKS * 2) {
        float v = Xb[(size_t)r * 128 + c];
        s += v; q += v * v;
    }
    ls[t] = s; lq[t] = q;
    __syncthreads();
    if (t < 128) {
        atomicAdd(&gsum[c], ls[t] + ls[t + 128]);
        atomicAdd(&gsq[c],  lq[t] + lq[t + 128]);
    }
}

__global__ void k_bnfinal(const float* __restrict__ gsum, const float* __restrict__ gsq,
                          const float* __restrict__ gamma, const float* __restrict__ beta,
                          float* __restrict__ scale, float* __restrict__ shift) {
    int c = threadIdx.x;
    float mu  = gsum[c] * (1.f / NN);
    float var = gsq[c] * (1.f / NN) - mu * mu;
    float sc  = gamma[c] * rsqrtf(var + 1e-5f);
    scale[c] = sc;
    shift[c] = beta[c] - mu * sc;
}

extern "C" void kernel_launch(void* const* d_in, const int* in_sizes, int n_in,
                              void* d_out, int out_size, void* d_ws, size_t ws_size,
                              hipStream_t stream)
{
    const float* x  = (const float*)d_in[0];
    const int*   ei = (const int*)d_in[1];
    const float* Wm[3]  = {(const float*)d_in[2], (const float*)d_in[6],  (const float*)d_in[10]};
    const float* Asr[3] = {(const float*)d_in[3], (const float*)d_in[7],  (const float*)d_in[11]};
    const float* Ads[3] = {(const float*)d_in[4], (const float*)d_in[8],  (const float*)d_in[12]};
    const float* Bs[3]  = {(const float*)d_in[5], (const float*)d_in[9],  (const float*)d_in[13]};
    const float* gam[2] = {(const float*)d_in[14], (const float*)d_in[16]};
    const float* bet[2] = {(const float*)d_in[15], (const float*)d_in[17]};

    char* p = (char*)d_ws;
    auto carve = [&](size_t bytes) -> char* {
        char* r = p;
        p += (bytes + 255) & ~(size_t)255;
        return r;
    };
    int*   off_  = (int*)carve((size_t)(NN + 1) * 4);
    int*   cur   = (int*)carve((size_t)NN * 4);
    int*   srcs  = (int*)carve((size_t)ET * 4);
    int*   bsum  = (int*)carve((size_t)NB * 4);
    int*   bpre  = (int*)carve((size_t)NB * 4);
    float* bufA  = (float*)carve((size_t)NN * 128 * 4);
    float* bufB  = (float*)carve((size_t)NN * 128 * 4);
    float* AS    = (float*)carve((size_t)NN * 4);
    float* AD    = (float*)carve((size_t)NN * 4);
    float* gsum  = (float*)carve(128 * 4);
    float* gsq   = (float*)carve(128 * 4);
    float* scale = (float*)carve(128 * 4);
    float* shift = (float*)carve(128 * 4);

    // CSR build (cur doubles as the count buffer, re-zeroed before scatter)
    hipMemsetAsync(cur, 0, (size_t)NN * 4, stream);
    k_count<<<(ET + 255) / 256, 256, 0, stream>>>(ei, cur);
    k_partial<<<NB, 256, 0, stream>>>(cur, bsum);
    k_scanbsum<<<1, 256, 0, stream>>>(bsum, bpre, off_);
    k_scanoff<<<NB, 512, 0, stream>>>(cur, bpre, off_);
    hipMemsetAsync(cur, 0, (size_t)NN * 4, stream);
    k_scatter<<<(ET + 255) / 256, 256, 0, stream>>>(ei, off_, cur, srcs);

    const int GEMM_GRID = (NN + 127) / 128;
    float* outp = (float*)d_out;

    // layer 0
    k_gemm<false><<<GEMM_GRID, 256, 0, stream>>>(x, Wm[0], nullptr, nullptr, Asr[0], Ads[0], bufA, AS, AD);
    k_agg<<<NN / 4, 256, 0, stream>>>(off_, srcs, bufA, AS, AD, Bs[0], bufB);
    hipMemsetAsync(gsum, 0, 128 * 4, stream);
    hipMemsetAsync(gsq, 0, 128 * 4, stream);
    k_colsum<<<STAT_BLOCKS, 256, 0, stream>>>(bufB, gsum, gsq);
    k_bnfinal<<<1, 128, 0, stream>>>(gsum, gsq, gam[0], bet[0], scale, shift);

    // layer 1
    k_gemm<true><<<GEMM_GRID, 256, 0, stream>>>(bufB, Wm[1], scale, shift, Asr[1], Ads[1], bufA, AS, AD);
    k_agg<<<NN / 4, 256, 0, stream>>>(off_, srcs, bufA, AS, AD, Bs[1], bufB);
    hipMemsetAsync(gsum, 0, 128 * 4, stream);
    hipMemsetAsync(gsq, 0, 128 * 4, stream);
    k_colsum<<<STAT_BLOCKS, 256, 0, stream>>>(bufB, gsum, gsq);
    k_bnfinal<<<1, 128, 0, stream>>>(gsum, gsq, gam[1], bet[1], scale, shift);

    // layer 2 (output straight to d_out)
    k_gemm<true><<<GEMM_GRID, 256, 0, stream>>>(bufB, Wm[2], scale, shift, Asr[2], Ads[2], bufA, AS, AD);
    k_agg<<<NN / 4, 256, 0, stream>>>(off_, srcs, bufA, AS, AD, Bs[2], outp);
}

// Round 2
// 777.927 us; speedup vs baseline: 1.1909x; 1.1909x over previous
//
#include <hip/hip_runtime.h>
#include <cstdint>
#include <cstddef>

#define NN 100000
#define NP 100096          // rows padded to multiple of 64
#define EE 1600000
#define ET 1700000         // EE + NN self-loops
#define NB 196             // ceil(NN/512)
#define STAT_BLOCKS 400

typedef short  bf16x8 __attribute__((ext_vector_type(8)));
typedef float  f32x4  __attribute__((ext_vector_type(4)));

__device__ __forceinline__ float leaky(float v) { return v > 0.f ? v : 0.2f * v; }

__device__ __forceinline__ unsigned short f2bf(float f) {
    unsigned int x = __builtin_bit_cast(unsigned int, f);
    x += 0x7FFFu + ((x >> 16) & 1u);   // RNE
    return (unsigned short)(x >> 16);
}
__device__ __forceinline__ float bflo(unsigned int u) {
    return __builtin_bit_cast(float, u << 16);
}
__device__ __forceinline__ float bfhi(unsigned int u) {
    return __builtin_bit_cast(float, u & 0xFFFF0000u);
}

// ---------------- CSR build ----------------
__global__ void k_count(const int* __restrict__ ei, int* __restrict__ cnt) {
    int e = blockIdx.x * 256 + threadIdx.x;
    if (e < ET) {
        int d = (e < EE) ? ei[EE + e] : (e - EE);
        atomicAdd(&cnt[d], 1);
    }
}

__global__ void k_partial(const int* __restrict__ cnt, int* __restrict__ bsum) {
    __shared__ int s[256];
    int t = threadIdx.x;
    int base = blockIdx.x * 512;
    int a = (base + t < NN) ? cnt[base + t] : 0;
    int b = (base + 256 + t < NN) ? cnt[base + 256 + t] : 0;
    s[t] = a + b;
    __syncthreads();
    for (int o = 128; o; o >>= 1) { if (t < o) s[t] += s[t + o]; __syncthreads(); }
    if (t == 0) bsum[blockIdx.x] = s[0];
}

__global__ void k_scanbsum(const int* __restrict__ bsum, int* __restrict__ bpre, int* __restrict__ off) {
    __shared__ int s[256];
    int t = threadIdx.x;
    int v = (t < NB) ? bsum[t] : 0;
    s[t] = v;
    __syncthreads();
    for (int o = 1; o < 256; o <<= 1) {
        int add = (t >= o) ? s[t - o] : 0;
        __syncthreads();
        s[t] += add;
        __syncthreads();
    }
    if (t < NB) bpre[t] = s[t] - v;
    if (t == 255) off[NN] = s[255];
}

__global__ void k_scanoff(const int* __restrict__ cnt, const int* __restrict__ bpre, int* __restrict__ off) {
    __shared__ int s[512];
    int t = threadIdx.x;
    int g = blockIdx.x * 512 + t;
    int v = (g < NN) ? cnt[g] : 0;
    s[t] = v;
    __syncthreads();
    for (int o = 1; o < 512; o <<= 1) {
        int add = (t >= o) ? s[t - o] : 0;
        __syncthreads();
        s[t] += add;
        __syncthreads();
    }
    if (g < NN) off[g] = bpre[blockIdx.x] + s[t] - v;
}

__global__ void k_scatter(const int* __restrict__ ei, const int* __restrict__ off,
                          int* __restrict__ cur, int* __restrict__ srcs) {
    int e = blockIdx.x * 256 + threadIdx.x;
    if (e < ET) {
        int s, d;
        if (e < EE) { s = ei[e]; d = ei[EE + e]; } else { s = e - EE; d = s; }
        int pos = off[d] + atomicAdd(&cur[d], 1);
        srcs[pos] = s;
    }
}

// ---------------- conversions ----------------
__global__ void k_cvtw(const float* __restrict__ W, unsigned short* __restrict__ Wb) {
    int i = blockIdx.x * 256 + threadIdx.x;   // 16384 elements
    Wb[i] = f2bf(W[i]);
}

// MODE 0: plain fp32->bf16; MODE 1: BN affine + relu + cvt
template<int MODE>
__global__ void k_prep(const float* __restrict__ src, const float* __restrict__ scale,
                       const float* __restrict__ shift, unsigned short* __restrict__ dst)
{
    int i4 = blockIdx.x * 256 + threadIdx.x;      // one float4 group
    if (i4 >= NP * 32) return;
    int row  = i4 >> 5;
    int col4 = (i4 & 31) << 2;
    float4 v = make_float4(0.f, 0.f, 0.f, 0.f);
    if (row < NN) {
        v = *(const float4*)&src[((size_t)row << 7) + col4];
        if (MODE) {
            float4 sc = *(const float4*)&scale[col4];
            float4 sh = *(const float4*)&shift[col4];
            v.x = fmaxf(0.f, fmaf(v.x, sc.x, sh.x));
            v.y = fmaxf(0.f, fmaf(v.y, sc.y, sh.y));
            v.z = fmaxf(0.f, fmaf(v.z, sc.z, sh.z));
            v.w = fmaxf(0.f, fmaf(v.w, sc.w, sh.w));
        }
    }
    ushort4 o;
    o.x = f2bf(v.x); o.y = f2bf(v.y); o.z = f2bf(v.z); o.w = f2bf(v.w);
    *(ushort4*)&dst[((size_t)row << 7) + col4] = o;
}

// ---------------- MFMA GEMM: H = X @ W^T (bf16 in, fp32 acc), fused AS/AD ----------------
// one wave computes a 16x128 strip; block = 4 waves = 64 rows
__global__ __launch_bounds__(256) void k_mfma(
    const unsigned short* __restrict__ Xb, const unsigned short* __restrict__ Wb,
    const float* __restrict__ asrc, const float* __restrict__ adst,
    unsigned short* __restrict__ Hb, float* __restrict__ AS, float* __restrict__ AD)
{
    __shared__ float hst[4][16][132];
    const int t    = threadIdx.x;
    const int w    = t >> 6;
    const int lane = t & 63;
    const int c    = lane & 15;    // fragment row index (m or n)
    const int q    = lane >> 4;    // quad -> k-subgroup
    const int r0   = blockIdx.x * 64 + w * 16;

    // A fragments: A[m = r0+c][k = k0*32 + q*8 + j]
    union { uint4 u; bf16x8 v; } Af[4];
    const size_t abase = ((size_t)(r0 + c) << 7) + (q << 3);
#pragma unroll
    for (int k0 = 0; k0 < 4; ++k0)
        Af[k0].u = *(const uint4*)(Xb + abase + (k0 << 5));

    f32x4 acc[8];
#pragma unroll
    for (int nt = 0; nt < 8; ++nt) acc[nt] = (f32x4){0.f, 0.f, 0.f, 0.f};

#pragma unroll
    for (int nt = 0; nt < 8; ++nt) {
        union { uint4 u; bf16x8 v; } Bf[4];
        const size_t bbase = ((size_t)(nt * 16 + c) << 7) + (q << 3);
#pragma unroll
        for (int k0 = 0; k0 < 4; ++k0)
            Bf[k0].u = *(const uint4*)(Wb + bbase + (k0 << 5));
#pragma unroll
        for (int k0 = 0; k0 < 4; ++k0)
            acc[nt] = __builtin_amdgcn_mfma_f32_16x16x32_bf16(Af[k0].v, Bf[k0].v, acc[nt], 0, 0, 0);
    }

    // fused AS/AD: per-row dot with a_src/a_dst; C/D layout col=lane&15, row=q*4+reg
    float ps[4] = {0.f, 0.f, 0.f, 0.f}, pd[4] = {0.f, 0.f, 0.f, 0.f};
#pragma unroll
    for (int nt = 0; nt < 8; ++nt) {
        float av = asrc[nt * 16 + c];
        float dv = adst[nt * 16 + c];
#pragma unroll
        for (int r = 0; r < 4; ++r) {
            ps[r] = fmaf(acc[nt][r], av, ps[r]);
            pd[r] = fmaf(acc[nt][r], dv, pd[r]);
        }
    }
#pragma unroll
    for (int m = 1; m < 16; m <<= 1) {
#pragma unroll
        for (int r = 0; r < 4; ++r) { ps[r] += __shfl_xor(ps[r], m); pd[r] += __shfl_xor(pd[r], m); }
    }
    if (c == 0) {
#pragma unroll
        for (int r = 0; r < 4; ++r) {
            int grow = r0 + q * 4 + r;
            if (grow < NN) { AS[grow] = ps[r]; AD[grow] = pd[r]; }
        }
    }

    // H store: dump C-layout to LDS, read back row-major, cvt to bf16
#pragma unroll
    for (int nt = 0; nt < 8; ++nt)
#pragma unroll
        for (int r = 0; r < 4; ++r)
            hst[w][q * 4 + r][nt * 16 + c] = acc[nt][r];
    __syncthreads();
    {
        const int row = lane >> 2, seg = lane & 3;
        const int grow = r0 + row;
        if (grow < NN) {
#pragma unroll
            for (int i = 0; i < 4; ++i) {
                float4 a = *(const float4*)&hst[w][row][seg * 32 + i * 8];
                float4 b = *(const float4*)&hst[w][row][seg * 32 + i * 8 + 4];
                ushort4 p1, p2;
                p1.x = f2bf(a.x); p1.y = f2bf(a.y); p1.z = f2bf(a.z); p1.w = f2bf(a.w);
                p2.x = f2bf(b.x); p2.y = f2bf(b.y); p2.z = f2bf(b.z); p2.w = f2bf(b.w);
                unsigned short* dp = Hb + ((size_t)grow << 7) + seg * 32 + i * 8;
                *(ushort4*)(dp)     = p1;
                *(ushort4*)(dp + 4) = p2;
            }
        }
    }
}

// ---------------- per-dst-node softmax + aggregation (bf16 H gather) ----------------
__global__ __launch_bounds__(256) void k_agg(
    const int* __restrict__ off, const int* __restrict__ srcs,
    const unsigned short* __restrict__ Hb, const float* __restrict__ AS,
    const float* __restrict__ AD, const float* __restrict__ bias,
    float* __restrict__ OUT)
{
    __shared__ int   s_src[4][64];
    __shared__ float s_ev[4][64];
    const int wid  = threadIdx.x >> 6;
    const int lane = threadIdx.x & 63;
    const int n    = blockIdx.x * 4 + wid;
    const int beg = off[n], end = off[n + 1];
    const float adn = AD[n];

    // pass 1: segment max
    float m = -1e30f;
    for (int i = beg + lane; i < end; i += 64) {
        float e = leaky(AS[srcs[i]] + adn);
        m = fmaxf(m, e);
    }
#pragma unroll
    for (int o = 32; o; o >>= 1) m = fmaxf(m, __shfl_xor(m, o));

    // pass 2: unnormalized accumulate + denom; lane covers cols 2*lane, 2*lane+1
    float acc0 = 0.f, acc1 = 0.f, den = 0.f;
    for (int base = beg; base < end; base += 64) {
        int cnt = end - base; if (cnt > 64) cnt = 64;
        float ev = 0.f; int s = 0;
        if (lane < cnt) {
            s  = srcs[base + lane];
            ev = __expf(leaky(AS[s] + adn) - m);
        }
        s_src[wid][lane] = s;
        s_ev[wid][lane]  = ev;
        den += ev;
        for (int j = 0; j < cnt; ++j) {
            int   sj = s_src[wid][j];
            float wg = s_ev[wid][j];
            unsigned int u = *(const unsigned int*)(Hb + ((size_t)sj << 7) + (lane << 1));
            acc0 = fmaf(wg, bflo(u), acc0);
            acc1 = fmaf(wg, bfhi(u), acc1);
        }
    }
#pragma unroll
    for (int o = 32; o; o >>= 1) den += __shfl_xor(den, o);
    float inv = 1.f / den;
    float2 bv = *(const float2*)&bias[lane << 1];
    float2 ov;
    ov.x = fmaf(acc0, inv, bv.x);
    ov.y = fmaf(acc1, inv, bv.y);
    *(float2*)&OUT[((size_t)n << 7) + (lane << 1)] = ov;
}

// ---------------- batchnorm stats -> per-column affine ----------------
__global__ void k_colsum(const float* __restrict__ Xf, float* __restrict__ gsum, float* __restrict__ gsq) {
    __shared__ float ls[256], lq[256];
    int t = threadIdx.x;
    int c = t & 127, half = t >> 7;
    float s = 0.f, q = 0.f;
    for (int r = blockIdx.x * 2 + half; r < NN; r += STAT_BLOCKS * 2) {
        float v = Xf[(size_t)r * 128 + c];
        s += v; q += v * v;
    }
    ls[t] = s; lq[t] = q;
    __syncthreads();
    if (t < 128) {
        atomicAdd(&gsum[c], ls[t] + ls[t + 128]);
        atomicAdd(&gsq[c],  lq[t] + lq[t + 128]);
    }
}

__global__ void k_bnfinal(const float* __restrict__ gsum, const float* __restrict__ gsq,
                          const float* __restrict__ gamma, const float* __restrict__ beta,
                          float* __restrict__ scale, float* __restrict__ shift) {
    int c = threadIdx.x;
    float mu  = gsum[c] * (1.f / NN);
    float var = gsq[c] * (1.f / NN) - mu * mu;
    float sc  = gamma[c] * rsqrtf(var + 1e-5f);
    scale[c] = sc;
    shift[c] = beta[c] - mu * sc;
}

extern "C" void kernel_launch(void* const* d_in, const int* in_sizes, int n_in,
                              void* d_out, int out_size, void* d_ws, size_t ws_size,
                              hipStream_t stream)
{
    const float* x  = (const float*)d_in[0];
    const int*   ei = (const int*)d_in[1];
    const float* Wm[3]  = {(const float*)d_in[2], (const float*)d_in[6],  (const float*)d_in[10]};
    const float* Asr[3] = {(const float*)d_in[3], (const float*)d_in[7],  (const float*)d_in[11]};
    const float* Ads[3] = {(const float*)d_in[4], (const float*)d_in[8],  (const float*)d_in[12]};
    const float* Bs[3]  = {(const float*)d_in[5], (const float*)d_in[9],  (const float*)d_in[13]};
    const float* gam[2] = {(const float*)d_in[14], (const float*)d_in[16]};
    const float* bet[2] = {(const float*)d_in[15], (const float*)d_in[17]};

    char* p = (char*)d_ws;
    auto carve = [&](size_t bytes) -> char* {
        char* r = p;
        p += (bytes + 255) & ~(size_t)255;
        return r;
    };
    int*   off_  = (int*)carve((size_t)(NN + 1) * 4);
    int*   cur   = (int*)carve((size_t)NN * 4);
    int*   srcs  = (int*)carve((size_t)ET * 4);
    int*   bsum  = (int*)carve((size_t)NB * 4);
    int*   bpre  = (int*)carve((size_t)NB * 4);
    unsigned short* Xb  = (unsigned short*)carve((size_t)NP * 128 * 2);
    unsigned short* Hb  = (unsigned short*)carve((size_t)NP * 128 * 2);
    unsigned short* Wb[3];
    Wb[0] = (unsigned short*)carve(16384 * 2);
    Wb[1] = (unsigned short*)carve(16384 * 2);
    Wb[2] = (unsigned short*)carve(16384 * 2);
    float* AS    = (float*)carve((size_t)NN * 4);
    float* AD    = (float*)carve((size_t)NN * 4);
    float* gsum  = (float*)carve(128 * 4);
    float* gsq   = (float*)carve(128 * 4);
    float* scale = (float*)carve(128 * 4);
    float* shift = (float*)carve(128 * 4);

    float* OUTf = (float*)d_out;   // fp32 intermediate lives in d_out (fully rewritten)

    // CSR build
    hipMemsetAsync(cur, 0, (size_t)NN * 4, stream);
    k_count<<<(ET + 255) / 256, 256, 0, stream>>>(ei, cur);
    k_partial<<<NB, 256, 0, stream>>>(cur, bsum);
    k_scanbsum<<<1, 256, 0, stream>>>(bsum, bpre, off_);
    k_scanoff<<<NB, 512, 0, stream>>>(cur, bpre, off_);
    hipMemsetAsync(cur, 0, (size_t)NN * 4, stream);
    k_scatter<<<(ET + 255) / 256, 256, 0, stream>>>(ei, off_, cur, srcs);

    // weight conversions
    k_cvtw<<<64, 256, 0, stream>>>(Wm[0], Wb[0]);
    k_cvtw<<<64, 256, 0, stream>>>(Wm[1], Wb[1]);
    k_cvtw<<<64, 256, 0, stream>>>(Wm[2], Wb[2]);

    const int PREP_GRID = (NP * 32 + 255) / 256;
    const int MFMA_GRID = NP / 64;

    // layer 0
    k_prep<0><<<PREP_GRID, 256, 0, stream>>>(x, nullptr, nullptr, Xb);
    k_mfma<<<MFMA_GRID, 256, 0, stream>>>(Xb, Wb[0], Asr[0], Ads[0], Hb, AS, AD);
    k_agg<<<NN / 4, 256, 0, stream>>>(off_, srcs, Hb, AS, AD, Bs[0], OUTf);
    hipMemsetAsync(gsum, 0, 128 * 4, stream);
    hipMemsetAsync(gsq, 0, 128 * 4, stream);
    k_colsum<<<STAT_BLOCKS, 256, 0, stream>>>(OUTf, gsum, gsq);
    k_bnfinal<<<1, 128, 0, stream>>>(gsum, gsq, gam[0], bet[0], scale, shift);

    // layer 1
    k_prep<1><<<PREP_GRID, 256, 0, stream>>>(OUTf, scale, shift, Xb);
    k_mfma<<<MFMA_GRID, 256, 0, stream>>>(Xb, Wb[1], Asr[1], Ads[1], Hb, AS, AD);
    k_agg<<<NN / 4, 256, 0, stream>>>(off_, srcs, Hb, AS, AD, Bs[1], OUTf);
    hipMemsetAsync(gsum, 0, 128 * 4, stream);
    hipMemsetAsync(gsq, 0, 128 * 4, stream);
    k_colsum<<<STAT_BLOCKS, 256, 0, stream>>>(OUTf, gsum, gsq);
    k_bnfinal<<<1, 128, 0, stream>>>(gsum, gsq, gam[1], bet[1], scale, shift);

    // layer 2 (k_agg writes final fp32 output into d_out)
    k_prep<1><<<PREP_GRID, 256, 0, stream>>>(OUTf, scale, shift, Xb);
    k_mfma<<<MFMA_GRID, 256, 0, stream>>>(Xb, Wb[2], Asr[2], Ads[2], Hb, AS, AD);
    k_agg<<<NN / 4, 256, 0, stream>>>(off_, srcs, Hb, AS, AD, Bs[2], OUTf);
}

// Round 3
// 646.879 us; speedup vs baseline: 1.4321x; 1.2026x over previous
//
#include <hip/hip_runtime.h>
#include <cstdint>
#include <cstddef>

#define NN 100000
#define NP 100096          // rows padded to multiple of 64
#define EE 1600000
#define ET 1700000         // EE + NN self-loops
#define NBKT 196           // ceil(NN/512) dst-range buckets
#define TILE 4096          // edges per k_bucket block
#define STAT_BLOCKS 400

typedef short  bf16x8 __attribute__((ext_vector_type(8)));
typedef float  f32x4  __attribute__((ext_vector_type(4)));

__device__ __forceinline__ float leaky(float v) { return v > 0.f ? v : 0.2f * v; }

__device__ __forceinline__ unsigned short f2bf(float f) {
    unsigned int x = __builtin_bit_cast(unsigned int, f);
    x += 0x7FFFu + ((x >> 16) & 1u);   // RNE
    return (unsigned short)(x >> 16);
}
__device__ __forceinline__ float bflo(unsigned int u) {
    return __builtin_bit_cast(float, u << 16);
}
__device__ __forceinline__ float bfhi(unsigned int u) {
    return __builtin_bit_cast(float, u & 0xFFFF0000u);
}

// ======================= CSR build via 2-level bucket sort =======================
// bucket = dst >> 9 (512 dsts per bucket); packed edge = (dst&511)<<17 | src

__global__ void k_bcount(const int* __restrict__ ei, int* __restrict__ btot) {
    __shared__ int h[256];
    int t = threadIdx.x;
    h[t] = 0;
    __syncthreads();
    for (int e = blockIdx.x * 256 + t; e < ET; e += 256 * 256) {
        int d = (e < EE) ? ei[EE + e] : (e - EE);
        atomicAdd(&h[d >> 9], 1);
    }
    __syncthreads();
    if (h[t]) atomicAdd(&btot[t], h[t]);
}

__global__ void k_bscan(const int* __restrict__ btot, int* __restrict__ bstart,
                        int* __restrict__ bcur, int* __restrict__ off) {
    __shared__ int s[256];
    int t = threadIdx.x;
    int v = (t < NBKT) ? btot[t] : 0;
    s[t] = v;
    __syncthreads();
    for (int o = 1; o < 256; o <<= 1) {
        int a = (t >= o) ? s[t - o] : 0;
        __syncthreads();
        s[t] += a;
        __syncthreads();
    }
    int ex = s[t] - v;
    if (t <= NBKT) bstart[t] = (t < NBKT) ? ex : ET;
    if (t == NBKT - 1) bstart[NBKT] = s[t];   // == ET
    bcur[t] = ex;
    if (t == 0) off[NN] = ET;
}

__global__ __launch_bounds__(256) void k_bucket(
    const int* __restrict__ ei, int* __restrict__ bcur, unsigned int* __restrict__ bucketed)
{
    __shared__ int hist[256], sc[256], loff[256], lcnt[256], gbase[256];
    __shared__ int stot;
    __shared__ unsigned int stage[TILE];
    __shared__ int gaddr[TILE];
    const int t = threadIdx.x;
    const int e0 = blockIdx.x * TILE;

    hist[t] = 0;
    __syncthreads();

    unsigned int pk[16];
    int bk[16];
#pragma unroll
    for (int i = 0; i < 16; ++i) {
        int e = e0 + i * 256 + t;
        bk[i] = -1;
        if (e < ET) {
            int s, d;
            if (e < EE) { s = ei[e]; d = ei[EE + e]; } else { s = e - EE; d = s; }
            bk[i] = d >> 9;
            pk[i] = ((unsigned int)(d & 511) << 17) | (unsigned int)s;
            atomicAdd(&hist[bk[i]], 1);
        }
    }
    __syncthreads();

    // exclusive scan of hist
    sc[t] = hist[t];
    __syncthreads();
    for (int o = 1; o < 256; o <<= 1) {
        int a = (t >= o) ? sc[t - o] : 0;
        __syncthreads();
        sc[t] += a;
        __syncthreads();
    }
    loff[t] = sc[t] - hist[t];
    lcnt[t] = 0;
    if (t == 255) stot = sc[255];
    if (t < NBKT && hist[t]) gbase[t] = atomicAdd(&bcur[t], hist[t]);
    __syncthreads();

    // rank + stage (value and its final global address)
#pragma unroll
    for (int i = 0; i < 16; ++i) {
        if (bk[i] >= 0) {
            int b = bk[i];
            int r = loff[b] + atomicAdd(&lcnt[b], 1);
            stage[r] = pk[i];
            gaddr[r] = gbase[b] + (r - loff[b]);
        }
    }
    __syncthreads();

    // coalesced-run writeout
    for (int j = t; j < stot; j += 256)
        bucketed[gaddr[j]] = stage[j];
}

__global__ __launch_bounds__(256) void k_csr(
    const unsigned int* __restrict__ bucketed, const int* __restrict__ bstart,
    int* __restrict__ off, int* __restrict__ srcs)
{
    __shared__ int h[512], sc2[512], c2[512], sp[256];
    const int t = threadIdx.x;
    const int b = blockIdx.x;
    const int beg = bstart[b], end = bstart[b + 1];
    const int cnt = end - beg;

    h[t] = 0; h[t + 256] = 0; c2[t] = 0; c2[t + 256] = 0;
    __syncthreads();
    for (int i = t; i < cnt; i += 256)
        atomicAdd(&h[bucketed[beg + i] >> 17], 1);
    __syncthreads();

    // exclusive scan of 512 via 256-thread pair scan
    int a0 = h[2 * t], a1 = h[2 * t + 1];
    sp[t] = a0 + a1;
    __syncthreads();
    for (int o = 1; o < 256; o <<= 1) {
        int a = (t >= o) ? sp[t - o] : 0;
        __syncthreads();
        sp[t] += a;
        __syncthreads();
    }
    int ep = sp[t] - (a0 + a1);
    sc2[2 * t] = ep;
    sc2[2 * t + 1] = ep + a0;
    __syncthreads();

    // write CSR offsets for this bucket's dsts
    const int d0 = b << 9;
#pragma unroll
    for (int k = t; k < 512; k += 256) {
        int d = d0 + k;
        if (d < NN) off[d] = beg + sc2[k];
    }

    // scatter srcs within the (L2-resident) bucket window
    for (int i = t; i < cnt; i += 256) {
        unsigned int v = bucketed[beg + i];
        int ld = v >> 17;
        int r = atomicAdd(&c2[ld], 1);
        srcs[beg + sc2[ld] + r] = (int)(v & 0x1FFFFu);
    }
}

// ======================= conversions =======================
__global__ void k_cvtw(const float* __restrict__ W, unsigned short* __restrict__ Wb) {
    int i = blockIdx.x * 256 + threadIdx.x;   // 16384 elements
    Wb[i] = f2bf(W[i]);
}

// MODE 0: plain fp32->bf16; MODE 1: BN affine + relu + cvt
template<int MODE>
__global__ void k_prep(const float* __restrict__ src, const float* __restrict__ scale,
                       const float* __restrict__ shift, unsigned short* __restrict__ dst)
{
    int i4 = blockIdx.x * 256 + threadIdx.x;      // one float4 group
    if (i4 >= NP * 32) return;
    int row  = i4 >> 5;
    int col4 = (i4 & 31) << 2;
    float4 v = make_float4(0.f, 0.f, 0.f, 0.f);
    if (row < NN) {
        v = *(const float4*)&src[((size_t)row << 7) + col4];
        if (MODE) {
            float4 sc = *(const float4*)&scale[col4];
            float4 sh = *(const float4*)&shift[col4];
            v.x = fmaxf(0.f, fmaf(v.x, sc.x, sh.x));
            v.y = fmaxf(0.f, fmaf(v.y, sc.y, sh.y));
            v.z = fmaxf(0.f, fmaf(v.z, sc.z, sh.z));
            v.w = fmaxf(0.f, fmaf(v.w, sc.w, sh.w));
        }
    }
    ushort4 o;
    o.x = f2bf(v.x); o.y = f2bf(v.y); o.z = f2bf(v.z); o.w = f2bf(v.w);
    *(ushort4*)&dst[((size_t)row << 7) + col4] = o;
}

// ======================= MFMA GEMM: H = X @ W^T, fused AS/AD =======================
__global__ __launch_bounds__(256) void k_mfma(
    const unsigned short* __restrict__ Xb, const unsigned short* __restrict__ Wb,
    const float* __restrict__ asrc, const float* __restrict__ adst,
    unsigned short* __restrict__ Hb, float* __restrict__ AS, float* __restrict__ AD)
{
    __shared__ float hst[4][16][132];
    const int t    = threadIdx.x;
    const int w    = t >> 6;
    const int lane = t & 63;
    const int c    = lane & 15;
    const int q    = lane >> 4;
    const int r0   = blockIdx.x * 64 + w * 16;

    union { uint4 u; bf16x8 v; } Af[4];
    const size_t abase = ((size_t)(r0 + c) << 7) + (q << 3);
#pragma unroll
    for (int k0 = 0; k0 < 4; ++k0)
        Af[k0].u = *(const uint4*)(Xb + abase + (k0 << 5));

    f32x4 acc[8];
#pragma unroll
    for (int nt = 0; nt < 8; ++nt) acc[nt] = (f32x4){0.f, 0.f, 0.f, 0.f};

#pragma unroll
    for (int nt = 0; nt < 8; ++nt) {
        union { uint4 u; bf16x8 v; } Bf[4];
        const size_t bbase = ((size_t)(nt * 16 + c) << 7) + (q << 3);
#pragma unroll
        for (int k0 = 0; k0 < 4; ++k0)
            Bf[k0].u = *(const uint4*)(Wb + bbase + (k0 << 5));
#pragma unroll
        for (int k0 = 0; k0 < 4; ++k0)
            acc[nt] = __builtin_amdgcn_mfma_f32_16x16x32_bf16(Af[k0].v, Bf[k0].v, acc[nt], 0, 0, 0);
    }

    // fused AS/AD; C/D layout col=lane&15, row=q*4+reg
    float ps[4] = {0.f, 0.f, 0.f, 0.f}, pd[4] = {0.f, 0.f, 0.f, 0.f};
#pragma unroll
    for (int nt = 0; nt < 8; ++nt) {
        float av = asrc[nt * 16 + c];
        float dv = adst[nt * 16 + c];
#pragma unroll
        for (int r = 0; r < 4; ++r) {
            ps[r] = fmaf(acc[nt][r], av, ps[r]);
            pd[r] = fmaf(acc[nt][r], dv, pd[r]);
        }
    }
#pragma unroll
    for (int m = 1; m < 16; m <<= 1) {
#pragma unroll
        for (int r = 0; r < 4; ++r) { ps[r] += __shfl_xor(ps[r], m); pd[r] += __shfl_xor(pd[r], m); }
    }
    if (c == 0) {
#pragma unroll
        for (int r = 0; r < 4; ++r) {
            int grow = r0 + q * 4 + r;
            if (grow < NN) { AS[grow] = ps[r]; AD[grow] = pd[r]; }
        }
    }

    // H store via LDS transpose, cvt to bf16
#pragma unroll
    for (int nt = 0; nt < 8; ++nt)
#pragma unroll
        for (int r = 0; r < 4; ++r)
            hst[w][q * 4 + r][nt * 16 + c] = acc[nt][r];
    __syncthreads();
    {
        const int row = lane >> 2, seg = lane & 3;
        const int grow = r0 + row;
        if (grow < NN) {
#pragma unroll
            for (int i = 0; i < 4; ++i) {
                float4 a = *(const float4*)&hst[w][row][seg * 32 + i * 8];
                float4 b = *(const float4*)&hst[w][row][seg * 32 + i * 8 + 4];
                ushort4 p1, p2;
                p1.x = f2bf(a.x); p1.y = f2bf(a.y); p1.z = f2bf(a.z); p1.w = f2bf(a.w);
                p2.x = f2bf(b.x); p2.y = f2bf(b.y); p2.z = f2bf(b.z); p2.w = f2bf(b.w);
                unsigned short* dp = Hb + ((size_t)grow << 7) + seg * 32 + i * 8;
                *(ushort4*)(dp)     = p1;
                *(ushort4*)(dp + 4) = p2;
            }
        }
    }
}

// ======================= per-dst softmax + aggregation =======================
__global__ __launch_bounds__(256) void k_agg(
    const int* __restrict__ off, const int* __restrict__ srcs,
    const unsigned short* __restrict__ Hb, const float* __restrict__ AS,
    const float* __restrict__ AD, const float* __restrict__ bias,
    float* __restrict__ OUT)
{
    __shared__ int   s_src[4][64];
    __shared__ float s_ev[4][64];
    const int wid  = threadIdx.x >> 6;
    const int lane = threadIdx.x & 63;
    const int n    = blockIdx.x * 4 + wid;
    const int beg = off[n], end = off[n + 1];
    const float adn = AD[n];

    float m = -1e30f;
    for (int i = beg + lane; i < end; i += 64) {
        float e = leaky(AS[srcs[i]] + adn);
        m = fmaxf(m, e);
    }
#pragma unroll
    for (int o = 32; o; o >>= 1) m = fmaxf(m, __shfl_xor(m, o));

    float acc0 = 0.f, acc1 = 0.f, den = 0.f;
    for (int base = beg; base < end; base += 64) {
        int cnt = end - base; if (cnt > 64) cnt = 64;
        float ev = 0.f; int s = 0;
        if (lane < cnt) {
            s  = srcs[base + lane];
            ev = __expf(leaky(AS[s] + adn) - m);
        }
        s_src[wid][lane] = s;
        s_ev[wid][lane]  = ev;
        den += ev;
        for (int j = 0; j < cnt; ++j) {
            int   sj = s_src[wid][j];
            float wg = s_ev[wid][j];
            unsigned int u = *(const unsigned int*)(Hb + ((size_t)sj << 7) + (lane << 1));
            acc0 = fmaf(wg, bflo(u), acc0);
            acc1 = fmaf(wg, bfhi(u), acc1);
        }
    }
#pragma unroll
    for (int o = 32; o; o >>= 1) den += __shfl_xor(den, o);
    float inv = 1.f / den;
    float2 bv = *(const float2*)&bias[lane << 1];
    float2 ov;
    ov.x = fmaf(acc0, inv, bv.x);
    ov.y = fmaf(acc1, inv, bv.y);
    *(float2*)&OUT[((size_t)n << 7) + (lane << 1)] = ov;
}

// ======================= batchnorm stats -> per-column affine =======================
__global__ void k_colsum(const float* __restrict__ Xf, float* __restrict__ gsum, float* __restrict__ gsq) {
    __shared__ float ls[256], lq[256];
    int t = threadIdx.x;
    int c = t & 127, half = t >> 7;
    float s = 0.f, q = 0.f;
    for (int r = blockIdx.x * 2 + half; r < NN; r += STAT_BLOCKS * 2) {
        float v = Xf[(size_t)r * 128 + c];
        s += v; q += v * v;
    }
    ls[t] = s; lq[t] = q;
    __syncthreads();
    if (t < 128) {
        atomicAdd(&gsum[c], ls[t] + ls[t + 128]);
        atomicAdd(&gsq[c],  lq[t] + lq[t + 128]);
    }
}

__global__ void k_bnfinal(const float* __restrict__ gsum, const float* __restrict__ gsq,
                          const float* __restrict__ gamma, const float* __restrict__ beta,
                          float* __restrict__ scale, float* __restrict__ shift) {
    int c = threadIdx.x;
    float mu  = gsum[c] * (1.f / NN);
    float var = gsq[c] * (1.f / NN) - mu * mu;
    float sc  = gamma[c] * rsqrtf(var + 1e-5f);
    scale[c] = sc;
    shift[c] = beta[c] - mu * sc;
}

extern "C" void kernel_launch(void* const* d_in, const int* in_sizes, int n_in,
                              void* d_out, int out_size, void* d_ws, size_t ws_size,
                              hipStream_t stream)
{
    const float* x  = (const float*)d_in[0];
    const int*   ei = (const int*)d_in[1];
    const float* Wm[3]  = {(const float*)d_in[2], (const float*)d_in[6],  (const float*)d_in[10]};
    const float* Asr[3] = {(const float*)d_in[3], (const float*)d_in[7],  (const float*)d_in[11]};
    const float* Ads[3] = {(const float*)d_in[4], (const float*)d_in[8],  (const float*)d_in[12]};
    const float* Bs[3]  = {(const float*)d_in[5], (const float*)d_in[9],  (const float*)d_in[13]};
    const float* gam[2] = {(const float*)d_in[14], (const float*)d_in[16]};
    const float* bet[2] = {(const float*)d_in[15], (const float*)d_in[17]};

    char* p = (char*)d_ws;
    auto carve = [&](size_t bytes) -> char* {
        char* r = p;
        p += (bytes + 255) & ~(size_t)255;
        return r;
    };
    int*   off_   = (int*)carve((size_t)(NN + 1) * 4);
    int*   srcs   = (int*)carve((size_t)ET * 4);
    unsigned int* bucketed = (unsigned int*)carve((size_t)ET * 4);
    int*   btot   = (int*)carve(256 * 4);
    int*   bstart = (int*)carve(260 * 4);
    int*   bcur   = (int*)carve(256 * 4);
    unsigned short* Xb  = (unsigned short*)carve((size_t)NP * 128 * 2);
    unsigned short* Hb  = (unsigned short*)carve((size_t)NP * 128 * 2);
    unsigned short* Wb[3];
    Wb[0] = (unsigned short*)carve(16384 * 2);
    Wb[1] = (unsigned short*)carve(16384 * 2);
    Wb[2] = (unsigned short*)carve(16384 * 2);
    float* AS    = (float*)carve((size_t)NN * 4);
    float* AD    = (float*)carve((size_t)NN * 4);
    float* gsum  = (float*)carve(128 * 4);
    float* gsq   = (float*)carve(128 * 4);
    float* scale = (float*)carve(128 * 4);
    float* shift = (float*)carve(128 * 4);

    float* OUTf = (float*)d_out;   // fp32 intermediate lives in d_out (fully rewritten)

    // CSR build (bucket sort)
    hipMemsetAsync(btot, 0, 256 * 4, stream);
    k_bcount<<<256, 256, 0, stream>>>(ei, btot);
    k_bscan<<<1, 256, 0, stream>>>(btot, bstart, bcur, off_);
    k_bucket<<<(ET + TILE - 1) / TILE, 256, 0, stream>>>(ei, bcur, bucketed);
    k_csr<<<NBKT, 256, 0, stream>>>(bucketed, bstart, off_, srcs);

    // weight conversions
    k_cvtw<<<64, 256, 0, stream>>>(Wm[0], Wb[0]);
    k_cvtw<<<64, 256, 0, stream>>>(Wm[1], Wb[1]);
    k_cvtw<<<64, 256, 0, stream>>>(Wm[2], Wb[2]);

    const int PREP_GRID = (NP * 32 + 255) / 256;
    const int MFMA_GRID = NP / 64;

    // layer 0
    k_prep<0><<<PREP_GRID, 256, 0, stream>>>(x, nullptr, nullptr, Xb);
    k_mfma<<<MFMA_GRID, 256, 0, stream>>>(Xb, Wb[0], Asr[0], Ads[0], Hb, AS, AD);
    k_agg<<<NN / 4, 256, 0, stream>>>(off_, srcs, Hb, AS, AD, Bs[0], OUTf);
    hipMemsetAsync(gsum, 0, 128 * 4, stream);
    hipMemsetAsync(gsq, 0, 128 * 4, stream);
    k_colsum<<<STAT_BLOCKS, 256, 0, stream>>>(OUTf, gsum, gsq);
    k_bnfinal<<<1, 128, 0, stream>>>(gsum, gsq, gam[0], bet[0], scale, shift);

    // layer 1
    k_prep<1><<<PREP_GRID, 256, 0, stream>>>(OUTf, scale, shift, Xb);
    k_mfma<<<MFMA_GRID, 256, 0, stream>>>(Xb, Wb[1], Asr[1], Ads[1], Hb, AS, AD);
    k_agg<<<NN / 4, 256, 0, stream>>>(off_, srcs, Hb, AS, AD, Bs[1], OUTf);
    hipMemsetAsync(gsum, 0, 128 * 4, stream);
    hipMemsetAsync(gsq, 0, 128 * 4, stream);
    k_colsum<<<STAT_BLOCKS, 256, 0, stream>>>(OUTf, gsum, gsq);
    k_bnfinal<<<1, 128, 0, stream>>>(gsum, gsq, gam[1], bet[1], scale, shift);

    // layer 2 (k_agg writes final fp32 output into d_out)
    k_prep<1><<<PREP_GRID, 256, 0, stream>>>(OUTf, scale, shift, Xb);
    k_mfma<<<MFMA_GRID, 256, 0, stream>>>(Xb, Wb[2], Asr[2], Ads[2], Hb, AS, AD);
    k_agg<<<NN / 4, 256, 0, stream>>>(off_, srcs, Hb, AS, AD, Bs[2], OUTf);
}

// Round 5
// 621.694 us; speedup vs baseline: 1.4901x; 1.0405x over previous
//
#include <hip/hip_runtime.h>
#include <cstdint>
#include <cstddef>

#define NN 100000
#define NP 100096          // rows padded to multiple of 64
#define EE 1600000
#define ET 1700000         // EE + NN self-loops
#define NBKT 196           // ceil(NN/512) dst-range buckets
#define TILE 2048          // edges per k_bucket block
#define STAT_BLOCKS 400

typedef short  bf16x8 __attribute__((ext_vector_type(8)));
typedef float  f32x4  __attribute__((ext_vector_type(4)));

__device__ __forceinline__ float leaky(float v) { return v > 0.f ? v : 0.2f * v; }

__device__ __forceinline__ unsigned short f2bf(float f) {
    unsigned int x = __builtin_bit_cast(unsigned int, f);
    x += 0x7FFFu + ((x >> 16) & 1u);   // RNE
    return (unsigned short)(x >> 16);
}
__device__ __forceinline__ unsigned int pk2(float lo, float hi) {
    return ((unsigned int)f2bf(hi) << 16) | (unsigned int)f2bf(lo);
}
__device__ __forceinline__ float bflo(unsigned int u) {
    return __builtin_bit_cast(float, u << 16);
}
__device__ __forceinline__ float bfhi(unsigned int u) {
    return __builtin_bit_cast(float, u & 0xFFFF0000u);
}

// ======================= CSR build via 2-level bucket sort =======================
// bucket = dst >> 9 (512 dsts per bucket); packed edge = (dst&511)<<17 | src

__global__ void k_bcount(const int* __restrict__ ei, int* __restrict__ btot) {
    __shared__ int h[256];
    int t = threadIdx.x;
    h[t] = 0;
    __syncthreads();
    for (int e = blockIdx.x * 256 + t; e < ET; e += 256 * 256) {
        int d = (e < EE) ? ei[EE + e] : (e - EE);
        atomicAdd(&h[d >> 9], 1);
    }
    __syncthreads();
    if (h[t]) atomicAdd(&btot[t], h[t]);
}

__global__ void k_bscan(const int* __restrict__ btot, int* __restrict__ bstart,
                        int* __restrict__ bcur, int* __restrict__ off) {
    __shared__ int s[256];
    int t = threadIdx.x;
    int v = (t < NBKT) ? btot[t] : 0;
    s[t] = v;
    __syncthreads();
    for (int o = 1; o < 256; o <<= 1) {
        int a = (t >= o) ? s[t - o] : 0;
        __syncthreads();
        s[t] += a;
        __syncthreads();
    }
    int ex = s[t] - v;
    if (t <= NBKT) bstart[t] = (t < NBKT) ? ex : ET;
    if (t == NBKT - 1) bstart[NBKT] = s[t];   // == ET
    bcur[t] = ex;
    if (t == 0) off[NN] = ET;
}

__global__ __launch_bounds__(256) void k_bucket(
    const int* __restrict__ ei, int* __restrict__ bcur, unsigned int* __restrict__ bucketed)
{
    __shared__ int h4[4][256], woff[4][256], loff[256], gbase[256], sc[256];
    __shared__ unsigned int stage[TILE];
    __shared__ int gaddr[TILE];
    __shared__ int stot_s;
    const int t = threadIdx.x;
    const int w = t >> 6;
    const int e0 = blockIdx.x * TILE;

    h4[0][t] = 0; h4[1][t] = 0; h4[2][t] = 0; h4[3][t] = 0;
    __syncthreads();

    unsigned int pk[TILE / 256];
    int bk[TILE / 256];
#pragma unroll
    for (int i = 0; i < TILE / 256; ++i) {
        int e = e0 + i * 256 + t;
        bk[i] = -1;
        if (e < ET) {
            int s, d;
            if (e < EE) { s = ei[e]; d = ei[EE + e]; } else { s = e - EE; d = s; }
            bk[i] = d >> 9;
            pk[i] = ((unsigned int)(d & 511) << 17) | (unsigned int)s;
            atomicAdd(&h4[w][bk[i]], 1);
        }
    }
    __syncthreads();

    // per-bucket totals + inclusive scan
    int h0 = h4[0][t], h1 = h4[1][t], h2 = h4[2][t], h3 = h4[3][t];
    int tot = h0 + h1 + h2 + h3;
    sc[t] = tot;
    __syncthreads();
    for (int o = 1; o < 256; o <<= 1) {
        int a = (t >= o) ? sc[t - o] : 0;
        __syncthreads();
        sc[t] += a;
        __syncthreads();
    }
    int lo = sc[t] - tot;
    loff[t] = lo;
    woff[0][t] = lo;
    woff[1][t] = lo + h0;
    woff[2][t] = lo + h0 + h1;
    woff[3][t] = lo + h0 + h1 + h2;
    if (t < NBKT && tot) gbase[t] = atomicAdd(&bcur[t], tot);
    if (t == 255) stot_s = sc[255];
    h4[0][t] = 0; h4[1][t] = 0; h4[2][t] = 0; h4[3][t] = 0;
    __syncthreads();

    // rank (per-wave counters -> 4x less LDS-atomic contention) + stage
#pragma unroll
    for (int i = 0; i < TILE / 256; ++i) {
        if (bk[i] >= 0) {
            int b = bk[i];
            int r = woff[w][b] + atomicAdd(&h4[w][b], 1);
            stage[r] = pk[i];
            gaddr[r] = gbase[b] + (r - loff[b]);
        }
    }
    __syncthreads();

    const int stot = stot_s;
    for (int j = t; j < stot; j += 256)
        bucketed[gaddr[j]] = stage[j];
}

__global__ __launch_bounds__(256) void k_csr(
    const unsigned int* __restrict__ bucketed, const int* __restrict__ bstart,
    int* __restrict__ off, int* __restrict__ srcs)
{
    __shared__ int h[512], sc2[512], c2[512], sp[256];
    const int t = threadIdx.x;
    const int b = blockIdx.x;
    const int beg = bstart[b], end = bstart[b + 1];
    const int cnt = end - beg;

    h[t] = 0; h[t + 256] = 0; c2[t] = 0; c2[t + 256] = 0;
    __syncthreads();
    for (int i = t; i < cnt; i += 256)
        atomicAdd(&h[bucketed[beg + i] >> 17], 1);
    __syncthreads();

    int a0 = h[2 * t], a1 = h[2 * t + 1];
    sp[t] = a0 + a1;
    __syncthreads();
    for (int o = 1; o < 256; o <<= 1) {
        int a = (t >= o) ? sp[t - o] : 0;
        __syncthreads();
        sp[t] += a;
        __syncthreads();
    }
    int ep = sp[t] - (a0 + a1);
    sc2[2 * t] = ep;
    sc2[2 * t + 1] = ep + a0;
    __syncthreads();

    const int d0 = b << 9;
#pragma unroll
    for (int k = t; k < 512; k += 256) {
        int d = d0 + k;
        if (d < NN) off[d] = beg + sc2[k];
    }

    for (int i = t; i < cnt; i += 256) {
        unsigned int v = bucketed[beg + i];
        int ld = v >> 17;
        int r = atomicAdd(&c2[ld], 1);
        srcs[beg + sc2[ld] + r] = (int)(v & 0x1FFFFu);
    }
}

// ======================= weight conversion =======================
__global__ void k_cvtw(const float* __restrict__ W, unsigned short* __restrict__ Wb) {
    int i = blockIdx.x * 256 + threadIdx.x;   // 16384 elements
    Wb[i] = f2bf(W[i]);
}

// ======================= MFMA GEMM: H = X @ W^T, fused affine/relu/cvt + AS/AD ===========
// MODE 0: plain fp32 read; MODE 1: BN affine + relu on the fly
template<int MODE>
__global__ __launch_bounds__(256) void k_mfma(
    const float* __restrict__ Xf, const unsigned short* __restrict__ Wb,
    const float* __restrict__ scale, const float* __restrict__ shift,
    const float* __restrict__ asrc, const float* __restrict__ adst,
    unsigned short* __restrict__ Hb, float* __restrict__ AS, float* __restrict__ AD)
{
    __shared__ float hst[4][16][132];
    const int t    = threadIdx.x;
    const int w    = t >> 6;
    const int lane = t & 63;
    const int c    = lane & 15;
    const int q    = lane >> 4;
    const int r0   = blockIdx.x * 64 + w * 16;
    const int row  = r0 + c;

    union { uint4 u; bf16x8 v; } Af[4];
    if (row < NN) {
        const float* xp = Xf + ((size_t)row << 7) + (q << 3);
#pragma unroll
        for (int k0 = 0; k0 < 4; ++k0) {
            float4 a = *(const float4*)(xp + (k0 << 5));
            float4 b = *(const float4*)(xp + (k0 << 5) + 4);
            if (MODE) {
                const int kb = (k0 << 5) + (q << 3);
                float4 sA = *(const float4*)&scale[kb];
                float4 sB = *(const float4*)&scale[kb + 4];
                float4 hA = *(const float4*)&shift[kb];
                float4 hB = *(const float4*)&shift[kb + 4];
                a.x = fmaxf(0.f, fmaf(a.x, sA.x, hA.x));
                a.y = fmaxf(0.f, fmaf(a.y, sA.y, hA.y));
                a.z = fmaxf(0.f, fmaf(a.z, sA.z, hA.z));
                a.w = fmaxf(0.f, fmaf(a.w, sA.w, hA.w));
                b.x = fmaxf(0.f, fmaf(b.x, sB.x, hB.x));
                b.y = fmaxf(0.f, fmaf(b.y, sB.y, hB.y));
                b.z = fmaxf(0.f, fmaf(b.z, sB.z, hB.z));
                b.w = fmaxf(0.f, fmaf(b.w, sB.w, hB.w));
            }
            Af[k0].u.x = pk2(a.x, a.y);
            Af[k0].u.y = pk2(a.z, a.w);
            Af[k0].u.z = pk2(b.x, b.y);
            Af[k0].u.w = pk2(b.z, b.w);
        }
    } else {
#pragma unroll
        for (int k0 = 0; k0 < 4; ++k0) Af[k0].u = make_uint4(0, 0, 0, 0);
    }

    f32x4 acc[8];
#pragma unroll
    for (int nt = 0; nt < 8; ++nt) acc[nt] = (f32x4){0.f, 0.f, 0.f, 0.f};

#pragma unroll
    for (int nt = 0; nt < 8; ++nt) {
        union { uint4 u; bf16x8 v; } Bf[4];
        const size_t bbase = ((size_t)(nt * 16 + c) << 7) + (q << 3);
#pragma unroll
        for (int k0 = 0; k0 < 4; ++k0)
            Bf[k0].u = *(const uint4*)(Wb + bbase + (k0 << 5));
#pragma unroll
        for (int k0 = 0; k0 < 4; ++k0)
            acc[nt] = __builtin_amdgcn_mfma_f32_16x16x32_bf16(Af[k0].v, Bf[k0].v, acc[nt], 0, 0, 0);
    }

    // fused AS/AD; C/D layout col=lane&15, row=q*4+reg
    float ps[4] = {0.f, 0.f, 0.f, 0.f}, pd[4] = {0.f, 0.f, 0.f, 0.f};
#pragma unroll
    for (int nt = 0; nt < 8; ++nt) {
        float av = asrc[nt * 16 + c];
        float dv = adst[nt * 16 + c];
#pragma unroll
        for (int r = 0; r < 4; ++r) {
            ps[r] = fmaf(acc[nt][r], av, ps[r]);
            pd[r] = fmaf(acc[nt][r], dv, pd[r]);
        }
    }
#pragma unroll
    for (int m = 1; m < 16; m <<= 1) {
#pragma unroll
        for (int r = 0; r < 4; ++r) { ps[r] += __shfl_xor(ps[r], m); pd[r] += __shfl_xor(pd[r], m); }
    }
    if (c == 0) {
#pragma unroll
        for (int r = 0; r < 4; ++r) {
            int grow = r0 + q * 4 + r;
            if (grow < NN) { AS[grow] = ps[r]; AD[grow] = pd[r]; }
        }
    }

    // H store via LDS transpose, pk-cvt to bf16
#pragma unroll
    for (int nt = 0; nt < 8; ++nt)
#pragma unroll
        for (int r = 0; r < 4; ++r)
            hst[w][q * 4 + r][nt * 16 + c] = acc[nt][r];
    __syncthreads();
    {
        const int orow = lane >> 2, seg = lane & 3;
        const int grow = r0 + orow;
        if (grow < NN) {
#pragma unroll
            for (int i = 0; i < 4; ++i) {
                float4 a = *(const float4*)&hst[w][orow][seg * 32 + i * 8];
                float4 b = *(const float4*)&hst[w][orow][seg * 32 + i * 8 + 4];
                uint4 o;
                o.x = pk2(a.x, a.y); o.y = pk2(a.z, a.w);
                o.z = pk2(b.x, b.y); o.w = pk2(b.z, b.w);
                *(uint4*)(Hb + ((size_t)grow << 7) + seg * 32 + i * 8) = o;
            }
        }
    }
}

// ======================= per-dst softmax + aggregation (single pass) =======================
// exp without max-subtraction: e = leaky(AS+AD) is O(1) for this model (softmax is
// shift-invariant; fp32 exp safe). 4 edges/iter, dwordx4 gather: 16 lanes x 16B per row.
__global__ __launch_bounds__(256) void k_agg(
    const int* __restrict__ off, const int* __restrict__ srcs,
    const unsigned short* __restrict__ Hb, const float* __restrict__ AS,
    const float* __restrict__ AD, const float* __restrict__ bias,
    float* __restrict__ OUT)
{
    __shared__ uint2 s_e[4][64];
    const int wid  = threadIdx.x >> 6;
    const int lane = threadIdx.x & 63;
    const int g    = lane >> 4;     // edge subgroup 0..3
    const int x16  = lane & 15;     // 16-lane column group
    const int n    = blockIdx.x * 4 + wid;
    const int beg = off[n], end = off[n + 1];
    const float adn = AD[n];

    float acc[8];
#pragma unroll
    for (int i = 0; i < 8; ++i) acc[i] = 0.f;
    float den = 0.f;

    for (int base = beg; base < end; base += 64) {
        int cnt = end - base; if (cnt > 64) cnt = 64;
        float wgt = 0.f; int s = 0;
        if (lane < cnt) {
            s = srcs[base + lane];
            float e = AS[s] + adn;
            e = (e > 0.f) ? e : 0.2f * e;
            wgt = __expf(e);
        }
        s_e[wid][lane] = make_uint2((unsigned int)s, __builtin_bit_cast(unsigned int, wgt));
        den += wgt;
        int rounds = (cnt + 3) >> 2;
        for (int j = 0; j < rounds; ++j) {
            uint2 ew = s_e[wid][(j << 2) + g];
            float wq = __builtin_bit_cast(float, ew.y);
            uint4 u = *((const uint4*)(Hb + ((size_t)ew.x << 7)) + x16);
            acc[0] = fmaf(wq, bflo(u.x), acc[0]);
            acc[1] = fmaf(wq, bfhi(u.x), acc[1]);
            acc[2] = fmaf(wq, bflo(u.y), acc[2]);
            acc[3] = fmaf(wq, bfhi(u.y), acc[3]);
            acc[4] = fmaf(wq, bflo(u.z), acc[4]);
            acc[5] = fmaf(wq, bfhi(u.z), acc[5]);
            acc[6] = fmaf(wq, bflo(u.w), acc[6]);
            acc[7] = fmaf(wq, bfhi(u.w), acc[7]);
        }
    }

    // reduce partial sums across the 4 edge subgroups; den across all 64 lanes
#pragma unroll
    for (int i = 0; i < 8; ++i) {
        acc[i] += __shfl_xor(acc[i], 16);
        acc[i] += __shfl_xor(acc[i], 32);
    }
#pragma unroll
    for (int o = 32; o; o >>= 1) den += __shfl_xor(den, o);
    float inv = 1.f / den;

    if (g == 0) {
        float4 b1 = *(const float4*)&bias[x16 << 3];
        float4 b2 = *(const float4*)&bias[(x16 << 3) + 4];
        float4 o1 = make_float4(fmaf(acc[0], inv, b1.x), fmaf(acc[1], inv, b1.y),
                                fmaf(acc[2], inv, b1.z), fmaf(acc[3], inv, b1.w));
        float4 o2 = make_float4(fmaf(acc[4], inv, b2.x), fmaf(acc[5], inv, b2.y),
                                fmaf(acc[6], inv, b2.z), fmaf(acc[7], inv, b2.w));
        float* op = OUT + ((size_t)n << 7) + (x16 << 3);
        *(float4*)op = o1;
        *(float4*)(op + 4) = o2;
    }
}

// ======================= batchnorm stats -> per-column affine =======================
__global__ void k_colsum(const float* __restrict__ Xf, float* __restrict__ gsum, float* __restrict__ gsq) {
    __shared__ float ls[256], lq[256];
    int t = threadIdx.x;
    int c = t & 127, half = t >> 7;
    float s = 0.f, q = 0.f;
    for (int r = blockIdx.x * 2 + half; r < NN; r += STAT_BLOCKS * 2) {
        float v = Xf[(size_t)r * 128 + c];
        s += v; q += v * v;
    }
    ls[t] = s; lq[t] = q;
    __syncthreads();
    if (t < 128) {
        atomicAdd(&gsum[c], ls[t] + ls[t + 128]);
        atomicAdd(&gsq[c],  lq[t] + lq[t + 128]);
    }
}

__global__ void k_bnfinal(const float* __restrict__ gsum, const float* __restrict__ gsq,
                          const float* __restrict__ gamma, const float* __restrict__ beta,
                          float* __restrict__ scale, float* __restrict__ shift) {
    int c = threadIdx.x;
    float mu  = gsum[c] * (1.f / NN);
    float var = gsq[c] * (1.f / NN) - mu * mu;
    float sc  = gamma[c] * rsqrtf(var + 1e-5f);
    scale[c] = sc;
    shift[c] = beta[c] - mu * sc;
}

extern "C" void kernel_launch(void* const* d_in, const int* in_sizes, int n_in,
                              void* d_out, int out_size, void* d_ws, size_t ws_size,
                              hipStream_t stream)
{
    const float* x  = (const float*)d_in[0];
    const int*   ei = (const int*)d_in[1];
    const float* Wm[3]  = {(const float*)d_in[2], (const float*)d_in[6],  (const float*)d_in[10]};
    const float* Asr[3] = {(const float*)d_in[3], (const float*)d_in[7],  (const float*)d_in[11]};
    const float* Ads[3] = {(const float*)d_in[4], (const float*)d_in[8],  (const float*)d_in[12]};
    const float* Bs[3]  = {(const float*)d_in[5], (const float*)d_in[9],  (const float*)d_in[13]};
    const float* gam[2] = {(const float*)d_in[14], (const float*)d_in[16]};
    const float* bet[2] = {(const float*)d_in[15], (const float*)d_in[17]};

    char* p = (char*)d_ws;
    auto carve = [&](size_t bytes) -> char* {
        char* r = p;
        p += (bytes + 255) & ~(size_t)255;
        return r;
    };
    int*   off_   = (int*)carve((size_t)(NN + 1) * 4);
    int*   srcs   = (int*)carve((size_t)ET * 4);
    unsigned int* bucketed = (unsigned int*)carve((size_t)ET * 4);
    int*   btot   = (int*)carve(256 * 4);
    int*   bstart = (int*)carve(260 * 4);
    int*   bcur   = (int*)carve(256 * 4);
    unsigned short* Hb  = (unsigned short*)carve((size_t)NP * 128 * 2);
    unsigned short* Wb[3];
    Wb[0] = (unsigned short*)carve(16384 * 2);
    Wb[1] = (unsigned short*)carve(16384 * 2);
    Wb[2] = (unsigned short*)carve(16384 * 2);
    float* AS    = (float*)carve((size_t)NN * 4);
    float* AD    = (float*)carve((size_t)NN * 4);
    float* gsum  = (float*)carve(128 * 4);
    float* gsq   = (float*)carve(128 * 4);
    float* scale = (float*)carve(128 * 4);
    float* shift = (float*)carve(128 * 4);

    float* OUTf = (float*)d_out;   // fp32 intermediate lives in d_out (fully rewritten)

    // CSR build (bucket sort)
    (void)hipMemsetAsync(btot, 0, 256 * 4, stream);
    k_bcount<<<256, 256, 0, stream>>>(ei, btot);
    k_bscan<<<1, 256, 0, stream>>>(btot, bstart, bcur, off_);
    k_bucket<<<(ET + TILE - 1) / TILE, 256, 0, stream>>>(ei, bcur, bucketed);
    k_csr<<<NBKT, 256, 0, stream>>>(bucketed, bstart, off_, srcs);

    // weight conversions
    k_cvtw<<<64, 256, 0, stream>>>(Wm[0], Wb[0]);
    k_cvtw<<<64, 256, 0, stream>>>(Wm[1], Wb[1]);
    k_cvtw<<<64, 256, 0, stream>>>(Wm[2], Wb[2]);

    const int MFMA_GRID = NP / 64;

    // layer 0
    k_mfma<0><<<MFMA_GRID, 256, 0, stream>>>(x, Wb[0], nullptr, nullptr, Asr[0], Ads[0], Hb, AS, AD);
    k_agg<<<NN / 4, 256, 0, stream>>>(off_, srcs, Hb, AS, AD, Bs[0], OUTf);
    (void)hipMemsetAsync(gsum, 0, 128 * 4, stream);
    (void)hipMemsetAsync(gsq, 0, 128 * 4, stream);
    k_colsum<<<STAT_BLOCKS, 256, 0, stream>>>(OUTf, gsum, gsq);
    k_bnfinal<<<1, 128, 0, stream>>>(gsum, gsq, gam[0], bet[0], scale, shift);

    // layer 1
    k_mfma<1><<<MFMA_GRID, 256, 0, stream>>>(OUTf, Wb[1], scale, shift, Asr[1], Ads[1], Hb, AS, AD);
    k_agg<<<NN / 4, 256, 0, stream>>>(off_, srcs, Hb, AS, AD, Bs[1], OUTf);
    (void)hipMemsetAsync(gsum, 0, 128 * 4, stream);
    (void)hipMemsetAsync(gsq, 0, 128 * 4, stream);
    k_colsum<<<STAT_BLOCKS, 256, 0, stream>>>(OUTf, gsum, gsq);
    k_bnfinal<<<1, 128, 0, stream>>>(gsum, gsq, gam[1], bet[1], scale, shift);

    // layer 2 (k_agg writes final fp32 output into d_out)
    k_mfma<1><<<MFMA_GRID, 256, 0, stream>>>(OUTf, Wb[2], scale, shift, Asr[2], Ads[2], Hb, AS, AD);
    k_agg<<<NN / 4, 256, 0, stream>>>(off_, srcs, Hb, AS, AD, Bs[2], OUTf);
}